// Round 9
// baseline (157.069 us; speedup 1.0000x reference)
//
#include <hip/hip_runtime.h>
#include <hip/hip_cooperative_groups.h>
#include <math.h>

namespace cg = cooperative_groups;

// scales: 0:{C=48,H=96,N=9216} 1:{96,48,2304} 2:{192,24,576} 3:{384,12,144}, B=2
// pixel-slot offsets (b-major within scale): {0, 18432, 23040, 24192}, total 24480
#define NSLOT 24480
#define MT 30      // Taylor terms m=0..29 of exp(q*e)
#define MTERM 3    // terms per moment vblock (keeps accumulators in registers)
#define MCH 10     // m-chunks (MTERM*MCH == MT)
#define NSL 3      // n-slices (partials summed in finish)
#define NVB_Q 270
#define NVB_M (8*MCH*NSL)   // 240
#define NVB_F 96
#define NVB_H 72
#define SMEMF 5232          // floats: max over phases (qkv: 3072+112+2048)

typedef float f32x4 __attribute__((ext_vector_type(4)));

struct FusedArgs {
  const float *x0, *x1, *x2, *x3;
  const float *w0, *w1, *w2, *w3;
  const float *c0, *c1, *c2, *c3;
  const float *wq[4], *bq[4], *wk[4], *bk[4], *wv[4], *bv[4];
  const float *wg0, *bg0, *wg1, *bg1, *wg2, *bg2;
  const float *wl0, *bl0, *bn_s, *bn_b, *bn_m, *bn_v, *wl1, *bl1;
  float *P, *V, *Q, *K, *KPART, *MOMP, *Y, *out;
};

// ---------------- Phase 1: conv1x1 + q/k/v, per-block k partial sums -------------
// CG channel-groups x PX pixels = 256 threads; every thread handles exactly 24 channels.
template<int CG>
__device__ __forceinline__ void qkv_phase(const FusedArgs& a, const int scale, const int C,
    const int N, const int slotoff, const int rel,
    const float* __restrict__ xp, const float* __restrict__ wp, const float* __restrict__ bp,
    float* smem) {
  float* s_w   = smem;           // 8*C <= 3072
  float* s_sm  = smem + 3072;    // 104 (0..7 bias |8..15 wq |16..23 wk |24..31 bv |32..95 wv^T |96 bq |97 bk)
  float* s_red = smem + 3184;    // 2048
  constexpr int PX = 256 / CG;
  constexpr int RW = (PX < 64) ? PX : 64;
  const int tid = threadIdx.x;
  for (int i = tid; i < 8*C; i += 256) { const int c = i >> 3, o = i & 7; s_w[i] = wp[o*C + c]; }
  if (tid >= 128 && tid < 192) { const int t = tid - 128; s_sm[32 + t] = a.wv[scale][(t & 7)*8 + (t >> 3)]; }
  if (tid < 8) {
    s_sm[tid]      = bp[tid];
    s_sm[8 + tid]  = a.wq[scale][tid];
    s_sm[16 + tid] = a.wk[scale][tid];
    s_sm[24 + tid] = a.bv[scale][tid];
  }
  if (tid == 96) { s_sm[96] = a.bq[scale][0]; s_sm[97] = a.bk[scale][0]; }
  __syncthreads();

  const int bpb = N / PX;                    // blocks per batch-half (exact)
  const int b = rel / bpb, blk = rel - b*bpb;
  const int px = tid & (PX - 1), cgi = tid / PX;
  const int n = blk*PX + px;
  const float* xb = xp + (size_t)b*C*N + n;
  float p[8];
  #pragma unroll
  for (int o = 0; o < 8; ++o) p[o] = 0.f;
  const int c0 = cgi*24;
  #pragma unroll
  for (int cc = 0; cc < 24; cc += 4) {
    const int c = c0 + cc;
    const float xv0 = xb[(size_t)(c+0)*N];
    const float xv1 = xb[(size_t)(c+1)*N];
    const float xv2 = xb[(size_t)(c+2)*N];
    const float xv3 = xb[(size_t)(c+3)*N];
    #pragma unroll
    for (int o = 0; o < 8; ++o) p[o] = fmaf(s_w[(c+0)*8+o], xv0, p[o]);
    #pragma unroll
    for (int o = 0; o < 8; ++o) p[o] = fmaf(s_w[(c+1)*8+o], xv1, p[o]);
    #pragma unroll
    for (int o = 0; o < 8; ++o) p[o] = fmaf(s_w[(c+2)*8+o], xv2, p[o]);
    #pragma unroll
    for (int o = 0; o < 8; ++o) p[o] = fmaf(s_w[(c+3)*8+o], xv3, p[o]);
  }
  f32x4* sp = (f32x4*)&s_red[tid*8];
  sp[0] = (f32x4){p[0], p[1], p[2], p[3]};
  sp[1] = (f32x4){p[4], p[5], p[6], p[7]};
  __syncthreads();

  const bool lead = (tid < PX);
  float pc[8], q = 0.f, kv = 0.f;
  if (lead) {
    #pragma unroll
    for (int o = 0; o < 8; ++o) {
      float s = s_sm[o];
      #pragma unroll
      for (int g = 0; g < CG; ++g) s += s_red[(g*PX + tid)*8 + o];
      pc[o] = s;
    }
    q = s_sm[96]; kv = s_sm[97];
    #pragma unroll
    for (int c = 0; c < 8; ++c) { q = fmaf(s_sm[8+c], pc[c], q); kv = fmaf(s_sm[16+c], pc[c], kv); }
  }
  __syncthreads();     // all reads of s_red done before reuse
  {
    float s = lead ? kv : 0.f;
    #pragma unroll
    for (int off = 1; off < RW; off <<= 1) s += __shfl_xor(s, off);   // stays within PX-lane groups
    if (lead && (tid & (RW - 1)) == 0) s_red[tid / RW] = s;
  }
  __syncthreads();
  if (tid == 0) {
    const float tot = (PX == 128) ? (s_red[0] + s_red[1]) : s_red[0];
    a.KPART[(scale*2 + b)*72 + blk] = tot;
  }
  if (lead) {
    float v[8];
    #pragma unroll
    for (int o = 0; o < 8; ++o) v[o] = s_sm[24 + o];
    #pragma unroll
    for (int c = 0; c < 8; ++c) {
      const float pcc = pc[c];
      #pragma unroll
      for (int o = 0; o < 8; ++o) v[o] = fmaf(s_sm[32 + c*8 + o], pcc, v[o]);
    }
    const int g = slotoff + b*N + n;
    f32x4* Pp = (f32x4*)&a.P[(size_t)g*8];
    Pp[0] = (f32x4){pc[0], pc[1], pc[2], pc[3]};
    Pp[1] = (f32x4){pc[4], pc[5], pc[6], pc[7]};
    f32x4* Vp = (f32x4*)&a.V[(size_t)g*8];
    Vp[0] = (f32x4){v[0], v[1], v[2], v[3]};
    Vp[1] = (f32x4){v[4], v[5], v[6], v[7]};
    a.Q[g] = q; a.K[g] = kv;
  }
}

// ---------------- Phase 2: partial moments of centered k against V ----------------
// d_m = sum e^m, M_m[c] = sum e^m v[c,k], e = k - kmean (softmax-invariant).
__device__ __forceinline__ void moments_phase(const FusedArgs& a, const int vb, float* smem) {
  float* s_km = smem;          // 1
  float* wred = smem + 16;     // 4*27
  const int tid = threadIdx.x;
  const int sb = vb / (MCH*NSL);
  const int r = vb - sb*(MCH*NSL);
  const int mch = r / NSL, nsl = r - mch*NSL;
  const int scale = sb >> 1, b = sb & 1;
  int N, off, nb;
  if (scale == 0)      { N = 9216; off = 0;     nb = 72; }
  else if (scale == 1) { N = 2304; off = 18432; nb = 36; }
  else if (scale == 2) { N = 576;  off = 23040; nb = 18; }
  else                 { N = 144;  off = 24192; nb = 9;  }
  const int base = off + b*N;

  if (tid < 64) {
    float s = 0.f;
    for (int i = tid; i < nb; i += 64) s += a.KPART[sb*72 + i];
    #pragma unroll
    for (int o2 = 32; o2 >= 1; o2 >>= 1) s += __shfl_xor(s, o2);
    if (tid == 0) s_km[0] = s / (float)N;
  }
  __syncthreads();
  const float kmean = s_km[0];

  const int L = N / NSL;
  const int i0 = nsl*L;
  const int m0 = mch*MTERM;
  float vals[MTERM*9];
  #pragma unroll
  for (int i = 0; i < MTERM*9; ++i) vals[i] = 0.f;
  for (int i = i0 + tid; i < i0 + L; i += 256) {
    const float e = a.K[base + i] - kmean;
    float pw = 1.f;
    for (int t = 0; t < m0; ++t) pw *= e;      // uniform per vblock
    const f32x4 v0 = *(const f32x4*)&a.V[(size_t)(base + i)*8];
    const f32x4 v1 = *(const f32x4*)&a.V[(size_t)(base + i)*8 + 4];
    #pragma unroll
    for (int m = 0; m < MTERM; ++m) {
      vals[m*9+0] += pw;
      vals[m*9+1] = fmaf(pw, v0.x, vals[m*9+1]);
      vals[m*9+2] = fmaf(pw, v0.y, vals[m*9+2]);
      vals[m*9+3] = fmaf(pw, v0.z, vals[m*9+3]);
      vals[m*9+4] = fmaf(pw, v0.w, vals[m*9+4]);
      vals[m*9+5] = fmaf(pw, v1.x, vals[m*9+5]);
      vals[m*9+6] = fmaf(pw, v1.y, vals[m*9+6]);
      vals[m*9+7] = fmaf(pw, v1.z, vals[m*9+7]);
      vals[m*9+8] = fmaf(pw, v1.w, vals[m*9+8]);
      pw *= e;
    }
  }
  #pragma unroll
  for (int i = 0; i < MTERM*9; ++i) {
    float v = vals[i];
    v += __shfl_xor(v, 32); v += __shfl_xor(v, 16); v += __shfl_xor(v, 8);
    v += __shfl_xor(v, 4);  v += __shfl_xor(v, 2);  v += __shfl_xor(v, 1);
    vals[i] = v;
  }
  const int wave = tid >> 6, lane = tid & 63;
  if (lane == 0) {
    #pragma unroll
    for (int i = 0; i < MTERM*9; ++i) wred[wave*27 + i] = vals[i];
  }
  __syncthreads();
  if (tid < MTERM*12) {   // MTERM m-slots x 12 floats (pad j=9..11 zeroed)
    const int m = tid / 12, j = tid - m*12;
    float t = 0.f;
    if (j < 9) { const int vi = m*9 + j; t = wred[0*27+vi] + wred[1*27+vi] + wred[2*27+vi] + wred[3*27+vi]; }
    a.MOMP[(size_t)nsl*2880 + (size_t)(sb*MT + m0 + m)*12 + j] = t;
  }
}

// ---------------- Phase 3: per-pixel Taylor softmax + wg conv + residual ----------
__device__ __forceinline__ void finish_phase(const FusedArgs& a, const int vb, float* smem) {
  float* smom = smem;          // 2880
  float* swg  = smem + 2880;   // 3*64
  float* sbg  = smem + 3072;   // 3*8
  const int tid = threadIdx.x;
  for (int i = tid; i < 2880; i += 256)
    smom[i] = a.MOMP[i] + a.MOMP[2880 + i] + a.MOMP[5760 + i];
  if (tid < 64) { swg[tid] = a.wg0[tid]; swg[64+tid] = a.wg1[tid]; swg[128+tid] = a.wg2[tid]; }
  if (tid < 8)  { sbg[tid] = a.bg0[tid]; sbg[8+tid] = a.bg1[tid]; sbg[16+tid] = a.bg2[tid]; }
  __syncthreads();
  const int g = vb*256 + tid;
  if (g < NSLOT) {
    int scale, N, off, widx;
    if (g < 18432)      { scale=0; N=9216; off=0;     widx=0; }
    else if (g < 23040) { scale=1; N=2304; off=18432; widx=1; }
    else if (g < 24192) { scale=2; N=576;  off=23040; widx=2; }
    else                { scale=3; N=144;  off=24192; widx=1; }  // scale3 uses cca1 (faithful)
    const int b = (g - off >= N) ? 1 : 0;
    const int sb = scale*2 + b;
    const float q = a.Q[g];
    const float* mb = &smom[sb*MT*12];
    float t = 1.f, den = 0.f;
    float num[8];
    #pragma unroll
    for (int c = 0; c < 8; ++c) num[c] = 0.f;
    #pragma unroll
    for (int m = 0; m < MT; ++m) {
      const f32x4 a0 = *(const f32x4*)&mb[m*12];
      const f32x4 a1 = *(const f32x4*)&mb[m*12 + 4];
      const f32x4 a2 = *(const f32x4*)&mb[m*12 + 8];
      den    = fmaf(t, a0.x, den);
      num[0] = fmaf(t, a0.y, num[0]); num[1] = fmaf(t, a0.z, num[1]); num[2] = fmaf(t, a0.w, num[2]);
      num[3] = fmaf(t, a1.x, num[3]); num[4] = fmaf(t, a1.y, num[4]); num[5] = fmaf(t, a1.z, num[5]);
      num[6] = fmaf(t, a1.w, num[6]); num[7] = fmaf(t, a2.x, num[7]);
      if (m + 1 < MT) t *= q * (1.f/(float)(m+1));   // unrolled -> constant folded
    }
    const float inv = 1.f/den;
    float o8[8];
    #pragma unroll
    for (int c = 0; c < 8; ++c) o8[c] = num[c]*inv;
    const f32x4 pA = *(const f32x4*)&a.P[(size_t)g*8];
    const f32x4 pB = *(const f32x4*)&a.P[(size_t)g*8 + 4];
    const float pv[8] = {pA.x, pA.y, pA.z, pA.w, pB.x, pB.y, pB.z, pB.w};
    const float* wg = &swg[widx*64];
    float y[8];
    #pragma unroll
    for (int o = 0; o < 8; ++o) {
      float s2 = pv[o] + sbg[widx*8 + o];
      #pragma unroll
      for (int c = 0; c < 8; ++c) s2 = fmaf(wg[o*8 + c], o8[c], s2);
      y[o] = s2;
    }
    f32x4* Yp = (f32x4*)&a.Y[(size_t)g*8];
    Yp[0] = (f32x4){y[0], y[1], y[2], y[3]};
    Yp[1] = (f32x4){y[4], y[5], y[6], y[7]};
  }
}

// ---------------- Phase 4: bilerp-concat + conv32 + BN + ReLU + conv19 ------------
template<int HS>
__device__ __forceinline__ void bilerp8(float* zo, const float* Yb, int h, int w) {
  constexpr float inv = (float)HS/96.0f;
  const float sy = (h + 0.5f)*inv - 0.5f;
  const float sx = (w + 0.5f)*inv - 0.5f;
  const int iy0 = (int)floorf(sy); const float fy = sy - (float)iy0;
  const int ix0 = (int)floorf(sx); const float fx = sx - (float)ix0;
  const int y0 = min(max(iy0, 0), HS-1), y1 = min(max(iy0 + 1, 0), HS-1);
  const int x0 = min(max(ix0, 0), HS-1), x1 = min(max(ix0 + 1, 0), HS-1);
  const float* p00 = &Yb[(size_t)(y0*HS + x0)*8];
  const float* p01 = &Yb[(size_t)(y0*HS + x1)*8];
  const float* p10 = &Yb[(size_t)(y1*HS + x0)*8];
  const float* p11 = &Yb[(size_t)(y1*HS + x1)*8];
  const float w00 = (1.f-fy)*(1.f-fx), w01 = (1.f-fy)*fx, w10 = fy*(1.f-fx), w11 = fy*fx;
  #pragma unroll
  for (int c = 0; c < 8; ++c)
    zo[c] = w00*p00[c] + w01*p01[c] + w10*p10[c] + w11*p11[c];
}

__device__ __forceinline__ void head_phase(const FusedArgs& a, const int vb, float* smem) {
  float* s_wl0 = smem;           // 1024
  float* s_wl1 = smem + 1024;    // 608
  float* s_bl0 = smem + 1632;    // 32
  float* s_sc  = smem + 1664;    // 32
  float* s_sh  = smem + 1696;    // 32
  float* s_bl1 = smem + 1728;    // 19
  const int tid = threadIdx.x;
  for (int i = tid; i < 1024; i += 256) s_wl0[i] = a.wl0[i];
  for (int i = tid; i < 608;  i += 256) s_wl1[i] = a.wl1[i];
  if (tid < 32) {
    s_bl0[tid] = a.bl0[tid];
    const float sc = a.bn_s[tid] / sqrtf(a.bn_v[tid] + 1e-5f);
    s_sc[tid] = sc;
    s_sh[tid] = a.bn_b[tid] - a.bn_m[tid]*sc;
  }
  if (tid >= 32 && tid < 51) s_bl1[tid - 32] = a.bl1[tid - 32];
  __syncthreads();
  const int gp = vb*256 + tid;   // exactly 18432 threads over 72 vblocks
  const int b = (gp >= 9216) ? 1 : 0;
  const int n = gp - b*9216;
  const int h = n / 96, w = n - h*96;
  float z[32];
  {
    const f32x4 zA = *(const f32x4*)&a.Y[(size_t)(b*9216 + n)*8];
    const f32x4 zB = *(const f32x4*)&a.Y[(size_t)(b*9216 + n)*8 + 4];
    z[0]=zA.x; z[1]=zA.y; z[2]=zA.z; z[3]=zA.w; z[4]=zB.x; z[5]=zB.y; z[6]=zB.z; z[7]=zB.w;
  }
  bilerp8<48>(z + 8,  &a.Y[(size_t)(18432 + b*2304)*8], h, w);
  bilerp8<24>(z + 16, &a.Y[(size_t)(23040 + b*576)*8],  h, w);
  bilerp8<12>(z + 24, &a.Y[(size_t)(24192 + b*144)*8],  h, w);
  float o19[19];
  #pragma unroll
  for (int j = 0; j < 19; ++j) o19[j] = s_bl1[j];
  #pragma unroll 1
  for (int o = 0; o < 32; ++o) {
    float s = s_bl0[o];
    #pragma unroll
    for (int c4 = 0; c4 < 8; ++c4) {
      const f32x4 wv = *(const f32x4*)&s_wl0[o*32 + c4*4];
      s = fmaf(wv.x, z[c4*4+0], s);
      s = fmaf(wv.y, z[c4*4+1], s);
      s = fmaf(wv.z, z[c4*4+2], s);
      s = fmaf(wv.w, z[c4*4+3], s);
    }
    const float t = fmaxf(fmaf(s, s_sc[o], s_sh[o]), 0.f);
    #pragma unroll
    for (int j = 0; j < 19; ++j) o19[j] = fmaf(s_wl1[j*32 + o], t, o19[j]);
  }
  #pragma unroll
  for (int j = 0; j < 19; ++j)
    a.out[((size_t)b*19 + j)*9216 + n] = o19[j];
}

// ---------------- Fused cooperative kernel ----------------------------------------
__global__ __launch_bounds__(256, 2) void fused_kernel(FusedArgs a) {
  __shared__ __align__(16) float smem[SMEMF];
  cg::grid_group grid = cg::this_grid();
  for (int vb = blockIdx.x; vb < NVB_Q; vb += gridDim.x) {
    if (vb < 144)      qkv_phase<2> (a, 0, 48,  9216, 0,     vb,     a.x0, a.w0, a.c0, smem);
    else if (vb < 216) qkv_phase<4> (a, 1, 96,  2304, 18432, vb-144, a.x1, a.w1, a.c1, smem);
    else if (vb < 252) qkv_phase<8> (a, 2, 192, 576,  23040, vb-216, a.x2, a.w2, a.c2, smem);
    else               qkv_phase<16>(a, 3, 384, 144,  24192, vb-252, a.x3, a.w3, a.c3, smem);
    __syncthreads();
  }
  grid.sync();
  for (int vb = blockIdx.x; vb < NVB_M; vb += gridDim.x) { moments_phase(a, vb, smem); __syncthreads(); }
  grid.sync();
  for (int vb = blockIdx.x; vb < NVB_F; vb += gridDim.x) { finish_phase(a, vb, smem); __syncthreads(); }
  grid.sync();
  for (int vb = blockIdx.x; vb < NVB_H; vb += gridDim.x) { head_phase(a, vb, smem); __syncthreads(); }
}

extern "C" void kernel_launch(void* const* d_in, const int* in_sizes, int n_in,
                              void* d_out, int out_size, void* d_ws, size_t ws_size,
                              hipStream_t stream) {
  (void)in_sizes; (void)n_in; (void)out_size; (void)ws_size;
  const float* wq[3]; const float* bq[3]; const float* wk[3]; const float* bk[3];
  const float* wv[3]; const float* bv[3]; const float* wg[3]; const float* bg[3];
  for (int i = 0; i < 3; ++i) {
    const int base = 12 + i*8;
    wq[i] = (const float*)d_in[base + 0]; bq[i] = (const float*)d_in[base + 1];
    wk[i] = (const float*)d_in[base + 2]; bk[i] = (const float*)d_in[base + 3];
    wv[i] = (const float*)d_in[base + 4]; bv[i] = (const float*)d_in[base + 5];
    wg[i] = (const float*)d_in[base + 6]; bg[i] = (const float*)d_in[base + 7];
  }
  const int m4[4] = {0, 1, 2, 1};   // scale -> cca index (scale3 reuses cca1, faithful)

  // workspace (floats): P[8N] V[8N] Q[N] K[N] KPART[576] MOMP[NSL*2880] Y[8N]  (~2.7 MB)
  float* ws = (float*)d_ws;
  FusedArgs fa;
  fa.P = ws;
  fa.V = fa.P + (size_t)NSLOT*8;
  fa.Q = fa.V + (size_t)NSLOT*8;
  fa.K = fa.Q + NSLOT;
  fa.KPART = fa.K + NSLOT;
  fa.MOMP = fa.KPART + 576;
  fa.Y = fa.MOMP + (size_t)NSL*2880;
  fa.out = (float*)d_out;

  fa.x0 = (const float*)d_in[0]; fa.x1 = (const float*)d_in[1];
  fa.x2 = (const float*)d_in[2]; fa.x3 = (const float*)d_in[3];
  fa.w0 = (const float*)d_in[4];  fa.c0 = (const float*)d_in[5];
  fa.w1 = (const float*)d_in[6];  fa.c1 = (const float*)d_in[7];
  fa.w2 = (const float*)d_in[8];  fa.c2 = (const float*)d_in[9];
  fa.w3 = (const float*)d_in[10]; fa.c3 = (const float*)d_in[11];
  for (int s = 0; s < 4; ++s) {
    fa.wq[s] = wq[m4[s]]; fa.bq[s] = bq[m4[s]];
    fa.wk[s] = wk[m4[s]]; fa.bk[s] = bk[m4[s]];
    fa.wv[s] = wv[m4[s]]; fa.bv[s] = bv[m4[s]];
  }
  fa.wg0 = wg[0]; fa.bg0 = bg[0];
  fa.wg1 = wg[1]; fa.bg1 = bg[1];
  fa.wg2 = wg[2]; fa.bg2 = bg[2];
  fa.wl0 = (const float*)d_in[36]; fa.bl0 = (const float*)d_in[37];
  fa.bn_s = (const float*)d_in[38]; fa.bn_b = (const float*)d_in[39];
  fa.bn_m = (const float*)d_in[40]; fa.bn_v = (const float*)d_in[41];
  fa.wl1 = (const float*)d_in[42]; fa.bl1 = (const float*)d_in[43];

  int maxB = 0;
  if (hipOccupancyMaxActiveBlocksPerMultiprocessor(&maxB, fused_kernel, 256, 0) != hipSuccess || maxB < 1)
    maxB = 1;
  int nCU = 0;
  {
    int dev = 0;
    hipGetDevice(&dev);
    hipDeviceProp_t prop;
    if (hipGetDeviceProperties(&prop, dev) == hipSuccess) nCU = prop.multiProcessorCount;
    if (nCU <= 0) nCU = 256;
  }
  long long cap = (long long)maxB * nCU;
  int grid = (cap < NVB_Q) ? (int)cap : NVB_Q;
  if (grid < 1) grid = 1;

  void* kargs[] = {(void*)&fa};
  hipLaunchCooperativeKernel(fused_kernel, dim3(grid), dim3(256), kargs, 0u, stream);
}

// Round 10
// 41.676 us; speedup vs baseline: 3.7689x; 3.7689x over previous
//
#include <hip/hip_runtime.h>
#include <math.h>

#define LB __launch_bounds__(256)

// scales: 0:{C=48,H=96,N=9216} 1:{96,48,2304} 2:{192,24,576} 3:{384,12,144}, B=2
// pixel-slot offsets (b-major within scale): {0, 18432, 23040, 24192}, total 24480
#define NSLOT 24480
#define MT 30      // Taylor terms m=0..29 of exp(q*e)
#define MTERM 3    // terms per moment block (27 accumulators - stays in registers)
#define MCH 10     // m-chunks (MTERM*MCH == MT)
#define NSL 6      // n-slices (partials summed in finish)

typedef float f32x4 __attribute__((ext_vector_type(4)));

struct QkvArgs {
  const float *x0, *x1, *x2, *x3;
  const float *w0, *w1, *w2, *w3;
  const float *c0, *c1, *c2, *c3;
  const float *wq[4], *bq[4], *wk[4], *bk[4], *wv[4], *bv[4];
  float *P, *V, *Q, *K, *KPART;
};

// CG channel-groups x PX pixels = 256 threads; every thread handles exactly 12 channels.
// Blocks are (scale,b)-uniform; per-block k-sum written to KPART (atomic-free, deterministic).
template<int CG>
__device__ __forceinline__ void qkv_body(const QkvArgs& a, const int scale, const int C,
    const int N, const int slotoff, const int rel,
    const float* __restrict__ xp, const float* __restrict__ wp, const float* __restrict__ bp,
    float* s_w, float* s_sm, float* s_red) {
  constexpr int PX = 256 / CG;
  constexpr int RW = (PX < 64) ? PX : 64;
  const int tid = threadIdx.x;
  for (int i = tid; i < 8*C; i += 256) { const int c = i >> 3, o = i & 7; s_w[i] = wp[o*C + c]; }
  if (tid >= 128 && tid < 192) { const int t = tid - 128; s_sm[32 + t] = a.wv[scale][(t & 7)*8 + (t >> 3)]; }
  if (tid < 8) {
    s_sm[tid]      = bp[tid];
    s_sm[8 + tid]  = a.wq[scale][tid];
    s_sm[16 + tid] = a.wk[scale][tid];
    s_sm[24 + tid] = a.bv[scale][tid];
  }
  if (tid == 96) { s_sm[96] = a.bq[scale][0]; s_sm[97] = a.bk[scale][0]; }
  __syncthreads();

  const int bpb = N / PX;                    // blocks per batch-half (exact by construction)
  const int b = rel / bpb, blk = rel - b*bpb;
  const int px = tid & (PX - 1), cg = tid / PX;
  const int n = blk*PX + px;
  const float* xb = xp + (size_t)b*C*N + n;
  float p[8];
  #pragma unroll
  for (int o = 0; o < 8; ++o) p[o] = 0.f;
  const int c0 = cg*12;
  #pragma unroll
  for (int cc = 0; cc < 12; cc += 4) {
    const int c = c0 + cc;
    const float xv0 = xb[(size_t)(c+0)*N];
    const float xv1 = xb[(size_t)(c+1)*N];
    const float xv2 = xb[(size_t)(c+2)*N];
    const float xv3 = xb[(size_t)(c+3)*N];
    #pragma unroll
    for (int o = 0; o < 8; ++o) p[o] = fmaf(s_w[(c+0)*8+o], xv0, p[o]);
    #pragma unroll
    for (int o = 0; o < 8; ++o) p[o] = fmaf(s_w[(c+1)*8+o], xv1, p[o]);
    #pragma unroll
    for (int o = 0; o < 8; ++o) p[o] = fmaf(s_w[(c+2)*8+o], xv2, p[o]);
    #pragma unroll
    for (int o = 0; o < 8; ++o) p[o] = fmaf(s_w[(c+3)*8+o], xv3, p[o]);
  }
  f32x4* sp = (f32x4*)&s_red[tid*8];
  sp[0] = (f32x4){p[0], p[1], p[2], p[3]};
  sp[1] = (f32x4){p[4], p[5], p[6], p[7]};
  __syncthreads();

  const bool lead = (tid < PX);
  float pc[8], q = 0.f, kv = 0.f;
  if (lead) {
    #pragma unroll
    for (int o = 0; o < 8; ++o) {
      float s = s_sm[o];
      #pragma unroll
      for (int g = 0; g < CG; ++g) s += s_red[(g*PX + tid)*8 + o];
      pc[o] = s;
    }
    q = s_sm[96]; kv = s_sm[97];
    #pragma unroll
    for (int c = 0; c < 8; ++c) { q = fmaf(s_sm[8+c], pc[c], q); kv = fmaf(s_sm[16+c], pc[c], kv); }
  }
  __syncthreads();     // all reads of s_red done before reuse
  {
    float s = lead ? kv : 0.f;
    #pragma unroll
    for (int off = 1; off < RW; off <<= 1) s += __shfl_xor(s, off);   // stays within PX-lane groups
    if (lead && (tid & (RW - 1)) == 0) s_red[tid / RW] = s;
  }
  __syncthreads();
  if (tid == 0) {
    a.KPART[(scale*2 + b)*144 + blk] = s_red[0];
  }
  if (lead) {
    float v[8];
    #pragma unroll
    for (int o = 0; o < 8; ++o) v[o] = s_sm[24 + o];
    #pragma unroll
    for (int c = 0; c < 8; ++c) {
      const float pcc = pc[c];
      #pragma unroll
      for (int o = 0; o < 8; ++o) v[o] = fmaf(s_sm[32 + c*8 + o], pcc, v[o]);
    }
    const int g = slotoff + b*N + n;
    f32x4* Pp = (f32x4*)&a.P[(size_t)g*8];
    Pp[0] = (f32x4){pc[0], pc[1], pc[2], pc[3]};
    Pp[1] = (f32x4){pc[4], pc[5], pc[6], pc[7]};
    f32x4* Vp = (f32x4*)&a.V[(size_t)g*8];
    Vp[0] = (f32x4){v[0], v[1], v[2], v[3]};
    Vp[1] = (f32x4){v[4], v[5], v[6], v[7]};
    a.Q[g] = q; a.K[g] = kv;
  }
}

// grid: 288 + 144 + 72 + 36 = 540 blocks (~2.1/CU, ~8.4 waves/CU)
__global__ LB void qkv_kernel(QkvArgs a) {
  __shared__ __align__(16) float s_w[3072];
  __shared__ __align__(16) float s_sm[104];
  __shared__ __align__(16) float s_red[256*8];
  const int bid = blockIdx.x;
  if (bid < 288)      qkv_body<4> (a, 0, 48,  9216, 0,     bid,     a.x0, a.w0, a.c0, s_w, s_sm, s_red);
  else if (bid < 432) qkv_body<8> (a, 1, 96,  2304, 18432, bid-288, a.x1, a.w1, a.c1, s_w, s_sm, s_red);
  else if (bid < 504) qkv_body<16>(a, 2, 192, 576,  23040, bid-432, a.x2, a.w2, a.c2, s_w, s_sm, s_red);
  else                qkv_body<32>(a, 3, 384, 144,  24192, bid-504, a.x3, a.w3, a.c3, s_w, s_sm, s_red);
}

// Partial moments of centered k against V: d_m = sum e^m, M_m[c] = sum e^m v[c,k], e = k - kmean.
// Grid: 8sb x MCH x NSL = 480 blocks; MTERM=3 accumulators (no spill).
// kmean from KPART partials, fixed-order reduce (deterministic).
__global__ LB void moments_kernel(const float* __restrict__ K, const float* __restrict__ V,
                                  const float* __restrict__ KPART, float* __restrict__ MOMP) {
  const int tid = threadIdx.x;
  const int bid = blockIdx.x;
  const int sb = bid / (MCH*NSL);
  const int r = bid - sb*(MCH*NSL);
  const int mch = r / NSL, nsl = r - mch*NSL;
  const int scale = sb >> 1, b = sb & 1;
  int N, off, nb;
  if (scale == 0)      { N = 9216; off = 0;     nb = 144; }
  else if (scale == 1) { N = 2304; off = 18432; nb = 72; }
  else if (scale == 2) { N = 576;  off = 23040; nb = 36; }
  else                 { N = 144;  off = 24192; nb = 18; }
  const int base = off + b*N;

  __shared__ float s_km;
  if (tid < 64) {
    float s = 0.f;
    for (int i = tid; i < nb; i += 64) s += KPART[sb*144 + i];
    #pragma unroll
    for (int o2 = 32; o2 >= 1; o2 >>= 1) s += __shfl_xor(s, o2);
    if (tid == 0) s_km = s / (float)N;
  }
  __syncthreads();
  const float kmean = s_km;

  const int L = N / NSL;
  const int i0 = nsl*L;
  const int m0 = mch*MTERM;
  float vals[MTERM*9];
  #pragma unroll
  for (int i = 0; i < MTERM*9; ++i) vals[i] = 0.f;
  for (int i = i0 + tid; i < i0 + L; i += 256) {
    const float e = K[base + i] - kmean;
    float pw = 1.f;
    for (int t = 0; t < m0; ++t) pw *= e;      // uniform per block
    const f32x4 v0 = *(const f32x4*)&V[(size_t)(base + i)*8];
    const f32x4 v1 = *(const f32x4*)&V[(size_t)(base + i)*8 + 4];
    #pragma unroll
    for (int m = 0; m < MTERM; ++m) {
      vals[m*9+0] += pw;
      vals[m*9+1] = fmaf(pw, v0.x, vals[m*9+1]);
      vals[m*9+2] = fmaf(pw, v0.y, vals[m*9+2]);
      vals[m*9+3] = fmaf(pw, v0.z, vals[m*9+3]);
      vals[m*9+4] = fmaf(pw, v0.w, vals[m*9+4]);
      vals[m*9+5] = fmaf(pw, v1.x, vals[m*9+5]);
      vals[m*9+6] = fmaf(pw, v1.y, vals[m*9+6]);
      vals[m*9+7] = fmaf(pw, v1.z, vals[m*9+7]);
      vals[m*9+8] = fmaf(pw, v1.w, vals[m*9+8]);
      pw *= e;
    }
  }
  #pragma unroll
  for (int i = 0; i < MTERM*9; ++i) {
    float v = vals[i];
    v += __shfl_xor(v, 32); v += __shfl_xor(v, 16); v += __shfl_xor(v, 8);
    v += __shfl_xor(v, 4);  v += __shfl_xor(v, 2);  v += __shfl_xor(v, 1);
    vals[i] = v;
  }
  __shared__ float wred[4][MTERM*9];
  const int wave = tid >> 6, lane = tid & 63;
  if (lane == 0) {
    #pragma unroll
    for (int i = 0; i < MTERM*9; ++i) wred[wave][i] = vals[i];
  }
  __syncthreads();
  if (tid < MTERM*12) {   // MTERM m-slots x 12 floats (pad j=9..11 zeroed)
    const int m = tid / 12, j = tid - m*12;
    float t = 0.f;
    if (j < 9) { const int vi = m*9 + j; t = wred[0][vi] + wred[1][vi] + wred[2][vi] + wred[3][vi]; }
    MOMP[(size_t)nsl*2880 + (size_t)(sb*MT + m0 + m)*12 + j] = t;
  }
}

struct FinArgs {
  const float *Q, *P, *MOMP;
  const float *wg0, *bg0, *wg1, *bg1, *wg2, *bg2;
  float *Y;
};

// Per pixel: out[c] = (sum_m t_m M_m[c]) / (sum_m t_m d_m), t_m = q^m/m!; y = P + wg*out + bg.
__global__ LB void finish_kernel(FinArgs a) {
  __shared__ __align__(16) float smom[8*MT*12];   // 2880 floats
  __shared__ float swg[3][64], sbg[3][8];
  const int tid = threadIdx.x;
  for (int i = tid; i < 8*MT*12; i += 256) {
    float s = a.MOMP[i];
    #pragma unroll
    for (int sl = 1; sl < NSL; ++sl) s += a.MOMP[(size_t)sl*2880 + i];
    smom[i] = s;
  }
  if (tid < 64) { swg[0][tid] = a.wg0[tid]; swg[1][tid] = a.wg1[tid]; swg[2][tid] = a.wg2[tid]; }
  if (tid < 8)  { sbg[0][tid] = a.bg0[tid]; sbg[1][tid] = a.bg1[tid]; sbg[2][tid] = a.bg2[tid]; }
  __syncthreads();
  const int g = blockIdx.x*256 + tid;
  if (g >= NSLOT) return;
  int scale, N, off, widx;
  if (g < 18432)      { scale=0; N=9216; off=0;     widx=0; }
  else if (g < 23040) { scale=1; N=2304; off=18432; widx=1; }
  else if (g < 24192) { scale=2; N=576;  off=23040; widx=2; }
  else                { scale=3; N=144;  off=24192; widx=1; }  // scale3 uses cca1 (faithful)
  const int b = (g - off >= N) ? 1 : 0;
  const int sb = scale*2 + b;
  const float q = a.Q[g];
  const float* mb = &smom[sb*MT*12];
  float t = 1.f, den = 0.f;
  float num[8];
  #pragma unroll
  for (int c = 0; c < 8; ++c) num[c] = 0.f;
  #pragma unroll
  for (int m = 0; m < MT; ++m) {
    const f32x4 a0 = *(const f32x4*)&mb[m*12];
    const f32x4 a1 = *(const f32x4*)&mb[m*12 + 4];
    const f32x4 a2 = *(const f32x4*)&mb[m*12 + 8];
    den    = fmaf(t, a0.x, den);
    num[0] = fmaf(t, a0.y, num[0]); num[1] = fmaf(t, a0.z, num[1]); num[2] = fmaf(t, a0.w, num[2]);
    num[3] = fmaf(t, a1.x, num[3]); num[4] = fmaf(t, a1.y, num[4]); num[5] = fmaf(t, a1.z, num[5]);
    num[6] = fmaf(t, a1.w, num[6]); num[7] = fmaf(t, a2.x, num[7]);
    if (m + 1 < MT) t *= q * (1.f/(float)(m+1));   // unrolled -> constant folded
  }
  const float inv = 1.f/den;
  float o8[8];
  #pragma unroll
  for (int c = 0; c < 8; ++c) o8[c] = num[c]*inv;
  const f32x4 pA = *(const f32x4*)&a.P[(size_t)g*8];
  const f32x4 pB = *(const f32x4*)&a.P[(size_t)g*8 + 4];
  const float pv[8] = {pA.x, pA.y, pA.z, pA.w, pB.x, pB.y, pB.z, pB.w};
  const float* wg = swg[widx];
  float y[8];
  #pragma unroll
  for (int o = 0; o < 8; ++o) {
    float s2 = pv[o] + sbg[widx][o];
    #pragma unroll
    for (int c = 0; c < 8; ++c) s2 = fmaf(wg[o*8 + c], o8[c], s2);
    y[o] = s2;
  }
  f32x4* Yp = (f32x4*)&a.Y[(size_t)g*8];
  Yp[0] = (f32x4){y[0], y[1], y[2], y[3]};
  Yp[1] = (f32x4){y[4], y[5], y[6], y[7]};
}

template<int HS>
__device__ inline void bilerp8(float* zo, const float* Yb, int h, int w) {
  constexpr float inv = (float)HS/96.0f;
  const float sy = (h + 0.5f)*inv - 0.5f;
  const float sx = (w + 0.5f)*inv - 0.5f;
  const int iy0 = (int)floorf(sy); const float fy = sy - (float)iy0;
  const int ix0 = (int)floorf(sx); const float fx = sx - (float)ix0;
  const int y0 = min(max(iy0, 0), HS-1), y1 = min(max(iy0 + 1, 0), HS-1);
  const int x0 = min(max(ix0, 0), HS-1), x1 = min(max(ix0 + 1, 0), HS-1);
  const float* p00 = &Yb[(size_t)(y0*HS + x0)*8];
  const float* p01 = &Yb[(size_t)(y0*HS + x1)*8];
  const float* p10 = &Yb[(size_t)(y1*HS + x0)*8];
  const float* p11 = &Yb[(size_t)(y1*HS + x1)*8];
  const float w00 = (1.f-fy)*(1.f-fx), w01 = (1.f-fy)*fx, w10 = fy*(1.f-fx), w11 = fy*fx;
  #pragma unroll
  for (int c = 0; c < 8; ++c)
    zo[c] = w00*p00[c] + w01*p01[c] + w10*p10[c] + w11*p11[c];
}

// 128-thread blocks; split fmaf chains; stream t through 19 static output accumulators.
__global__ __launch_bounds__(128) void head_kernel(const float* __restrict__ Y,
                               const float* wl0, const float* bl0,
                               const float* bn_s, const float* bn_b,
                               const float* bn_m, const float* bn_v,
                               const float* wl1, const float* bl1,
                               float* __restrict__ out) {
  __shared__ float s_wl0[1024], s_wl1[608];
  __shared__ float s_bl0[32], s_sc[32], s_sh[32], s_bl1[19];
  const int tid = threadIdx.x;
  for (int i = tid; i < 1024; i += 128) s_wl0[i] = wl0[i];
  for (int i = tid; i < 608;  i += 128) s_wl1[i] = wl1[i];
  if (tid < 32) {
    s_bl0[tid] = bl0[tid];
    const float sc = bn_s[tid] / sqrtf(bn_v[tid] + 1e-5f);
    s_sc[tid] = sc;
    s_sh[tid] = bn_b[tid] - bn_m[tid]*sc;
  }
  if (tid >= 32 && tid < 51) s_bl1[tid - 32] = bl1[tid - 32];
  __syncthreads();
  const int gp = blockIdx.x*128 + tid;   // exactly 18432 threads
  const int b = (gp >= 9216) ? 1 : 0;
  const int n = gp - b*9216;
  const int h = n / 96, w = n - h*96;
  float z[32];
  {
    const float4 zA = *(const float4*)&Y[(size_t)(b*9216 + n)*8];
    const float4 zB = *(const float4*)&Y[(size_t)(b*9216 + n)*8 + 4];
    z[0]=zA.x; z[1]=zA.y; z[2]=zA.z; z[3]=zA.w; z[4]=zB.x; z[5]=zB.y; z[6]=zB.z; z[7]=zB.w;
  }
  bilerp8<48>(z + 8,  &Y[(size_t)(18432 + b*2304)*8], h, w);
  bilerp8<24>(z + 16, &Y[(size_t)(23040 + b*576)*8],  h, w);
  bilerp8<12>(z + 24, &Y[(size_t)(24192 + b*144)*8],  h, w);
  float o19[19];
  #pragma unroll
  for (int j = 0; j < 19; ++j) o19[j] = s_bl1[j];
  #pragma unroll 1
  for (int o = 0; o < 32; ++o) {
    float sA = s_bl0[o], sB = 0.f;   // two chains halve the dependency stall
    #pragma unroll
    for (int c4 = 0; c4 < 4; ++c4) {
      const float4 wv = *(const float4*)&s_wl0[o*32 + c4*4];
      sA = fmaf(wv.x, z[c4*4+0], sA);
      sA = fmaf(wv.y, z[c4*4+1], sA);
      sA = fmaf(wv.z, z[c4*4+2], sA);
      sA = fmaf(wv.w, z[c4*4+3], sA);
    }
    #pragma unroll
    for (int c4 = 4; c4 < 8; ++c4) {
      const float4 wv = *(const float4*)&s_wl0[o*32 + c4*4];
      sB = fmaf(wv.x, z[c4*4+0], sB);
      sB = fmaf(wv.y, z[c4*4+1], sB);
      sB = fmaf(wv.z, z[c4*4+2], sB);
      sB = fmaf(wv.w, z[c4*4+3], sB);
    }
    const float t = fmaxf(fmaf(sA + sB, s_sc[o], s_sh[o]), 0.f);
    #pragma unroll
    for (int j = 0; j < 19; ++j) o19[j] = fmaf(s_wl1[j*32 + o], t, o19[j]);
  }
  #pragma unroll
  for (int j = 0; j < 19; ++j)
    out[((size_t)b*19 + j)*9216 + n] = o19[j];
}

extern "C" void kernel_launch(void* const* d_in, const int* in_sizes, int n_in,
                              void* d_out, int out_size, void* d_ws, size_t ws_size,
                              hipStream_t stream) {
  (void)in_sizes; (void)n_in; (void)out_size; (void)ws_size;
  const float* wq[3]; const float* bq[3]; const float* wk[3]; const float* bk[3];
  const float* wv[3]; const float* bv[3]; const float* wg[3]; const float* bg[3];
  for (int i = 0; i < 3; ++i) {
    const int base = 12 + i*8;
    wq[i] = (const float*)d_in[base + 0]; bq[i] = (const float*)d_in[base + 1];
    wk[i] = (const float*)d_in[base + 2]; bk[i] = (const float*)d_in[base + 3];
    wv[i] = (const float*)d_in[base + 4]; bv[i] = (const float*)d_in[base + 5];
    wg[i] = (const float*)d_in[base + 6]; bg[i] = (const float*)d_in[base + 7];
  }
  const int m4[4] = {0, 1, 2, 1};   // scale -> cca index (scale3 reuses cca1, faithful)

  // workspace (floats): P[8N] V[8N] Q[N] K[N] KPART[1152] MOMP[NSL*2880] Y[8N]  (~2.7 MB)
  float* ws = (float*)d_ws;
  float* P = ws;
  float* V = P + (size_t)NSLOT*8;
  float* Q = V + (size_t)NSLOT*8;
  float* K = Q + NSLOT;
  float* KPART = K + NSLOT;
  float* MOMP = KPART + 1152;
  float* Y = MOMP + (size_t)NSL*2880;

  QkvArgs qa;
  qa.x0 = (const float*)d_in[0]; qa.x1 = (const float*)d_in[1];
  qa.x2 = (const float*)d_in[2]; qa.x3 = (const float*)d_in[3];
  qa.w0 = (const float*)d_in[4];  qa.c0 = (const float*)d_in[5];
  qa.w1 = (const float*)d_in[6];  qa.c1 = (const float*)d_in[7];
  qa.w2 = (const float*)d_in[8];  qa.c2 = (const float*)d_in[9];
  qa.w3 = (const float*)d_in[10]; qa.c3 = (const float*)d_in[11];
  for (int s = 0; s < 4; ++s) {
    qa.wq[s] = wq[m4[s]]; qa.bq[s] = bq[m4[s]];
    qa.wk[s] = wk[m4[s]]; qa.bk[s] = bk[m4[s]];
    qa.wv[s] = wv[m4[s]]; qa.bv[s] = bv[m4[s]];
  }
  qa.P = P; qa.V = V; qa.Q = Q; qa.K = K; qa.KPART = KPART;

  FinArgs fa;
  fa.Q = Q; fa.P = P; fa.MOMP = MOMP;
  fa.wg0 = wg[0]; fa.bg0 = bg[0];
  fa.wg1 = wg[1]; fa.bg1 = bg[1];
  fa.wg2 = wg[2]; fa.bg2 = bg[2];
  fa.Y = Y;

  qkv_kernel<<<540, 256, 0, stream>>>(qa);
  moments_kernel<<<8*MCH*NSL, 256, 0, stream>>>(K, V, KPART, MOMP);
  finish_kernel<<<96, 256, 0, stream>>>(fa);
  head_kernel<<<144, 128, 0, stream>>>(Y, (const float*)d_in[36], (const float*)d_in[37],
                                      (const float*)d_in[38], (const float*)d_in[39],
                                      (const float*)d_in[40], (const float*)d_in[41],
                                      (const float*)d_in[42], (const float*)d_in[43],
                                      (float*)d_out);
}

// Round 11
// 35.277 us; speedup vs baseline: 4.4525x; 1.1814x over previous
//
#include <hip/hip_runtime.h>
#include <math.h>

#define LB __launch_bounds__(256)

// scales: 0:{C=48,H=96,N=9216} 1:{96,48,2304} 2:{192,24,576} 3:{384,12,144}, B=2
// pixel-slot offsets (b-major within scale): {0, 18432, 23040, 24192}, total 24480
#define NSLOT 24480
#define MT 28        // Taylor terms m=0..27 of exp(q*k); 9*MT = 252 <= 256 threads
#define NMOM 252     // values per (scale,b): [m][j], j=0 -> d_m, j=1..8 -> M_m[j-1]

typedef float f32x4 __attribute__((ext_vector_type(4)));

struct QkvmArgs {
  const float *x0, *x1, *x2, *x3;
  const float *w0, *w1, *w2, *w3;
  const float *c0, *c1, *c2, *c3;
  const float *wq[4], *bq[4], *wk[4], *bk[4], *wv[4], *bv[4];
  float *P, *Q;
  unsigned long long *MOM;   // [8][NMOM] fixed-point moments, scale 2^(30-m)
};

// CG channel-groups x PX pixels = 256 threads; each thread handles exactly 12 channels.
// Block computes conv+q/k/v for PX pixels, then its 252 moment partials in fixed order,
// and accumulates them with int64 fixed-point atomics (order-invariant -> deterministic).
template<int CG>
__device__ __forceinline__ void qkvm_body(const QkvmArgs& a, const int scale, const int C,
    const int N, const int slotoff, const int rel,
    const float* __restrict__ xp, const float* __restrict__ wp, const float* __restrict__ bp,
    float* s_w, float* s_sm, float* s_red, float* s_kp, float* s_v) {
  constexpr int PX = 256 / CG;
  const int tid = threadIdx.x;
  for (int i = tid; i < 8*C; i += 256) { const int c = i >> 3, o = i & 7; s_w[i] = wp[o*C + c]; }
  if (tid >= 128 && tid < 192) { const int t = tid - 128; s_sm[32 + t] = a.wv[scale][(t & 7)*8 + (t >> 3)]; }
  if (tid < 8) {
    s_sm[tid]      = bp[tid];
    s_sm[8 + tid]  = a.wq[scale][tid];
    s_sm[16 + tid] = a.wk[scale][tid];
    s_sm[24 + tid] = a.bv[scale][tid];
  }
  if (tid == 96) { s_sm[96] = a.bq[scale][0]; s_sm[97] = a.bk[scale][0]; }
  __syncthreads();

  const int bpb = N / PX;                    // blocks per batch-half (exact by construction)
  const int b = rel / bpb, blk = rel - b*bpb;
  const int px = tid & (PX - 1), cg = tid / PX;
  const int n = blk*PX + px;
  const float* xb = xp + (size_t)b*C*N + n;
  float p[8];
  #pragma unroll
  for (int o = 0; o < 8; ++o) p[o] = 0.f;
  const int c0 = cg*12;
  #pragma unroll
  for (int cc = 0; cc < 12; cc += 4) {
    const int c = c0 + cc;
    const float xv0 = xb[(size_t)(c+0)*N];
    const float xv1 = xb[(size_t)(c+1)*N];
    const float xv2 = xb[(size_t)(c+2)*N];
    const float xv3 = xb[(size_t)(c+3)*N];
    #pragma unroll
    for (int o = 0; o < 8; ++o) p[o] = fmaf(s_w[(c+0)*8+o], xv0, p[o]);
    #pragma unroll
    for (int o = 0; o < 8; ++o) p[o] = fmaf(s_w[(c+1)*8+o], xv1, p[o]);
    #pragma unroll
    for (int o = 0; o < 8; ++o) p[o] = fmaf(s_w[(c+2)*8+o], xv2, p[o]);
    #pragma unroll
    for (int o = 0; o < 8; ++o) p[o] = fmaf(s_w[(c+3)*8+o], xv3, p[o]);
  }
  f32x4* sp = (f32x4*)&s_red[tid*8];
  sp[0] = (f32x4){p[0], p[1], p[2], p[3]};
  sp[1] = (f32x4){p[4], p[5], p[6], p[7]};
  __syncthreads();

  if (tid < PX) {
    float pc[8];
    #pragma unroll
    for (int o = 0; o < 8; ++o) {
      float s = s_sm[o];
      #pragma unroll
      for (int g = 0; g < CG; ++g) s += s_red[(g*PX + tid)*8 + o];
      pc[o] = s;
    }
    float q = s_sm[96], kv = s_sm[97];
    #pragma unroll
    for (int c = 0; c < 8; ++c) { q = fmaf(s_sm[8+c], pc[c], q); kv = fmaf(s_sm[16+c], pc[c], kv); }
    float v[8];
    #pragma unroll
    for (int o = 0; o < 8; ++o) v[o] = s_sm[24 + o];
    #pragma unroll
    for (int c = 0; c < 8; ++c) {
      const float pcc = pc[c];
      #pragma unroll
      for (int o = 0; o < 8; ++o) v[o] = fmaf(s_sm[32 + c*8 + o], pcc, v[o]);
    }
    const int g = slotoff + b*N + n;
    f32x4* Pp = (f32x4*)&a.P[(size_t)g*8];
    Pp[0] = (f32x4){pc[0], pc[1], pc[2], pc[3]};
    Pp[1] = (f32x4){pc[4], pc[5], pc[6], pc[7]};
    a.Q[g] = q;
    // stage k-powers and v for the in-block moment reduction
    s_kp[tid*MT] = 1.f;
    float pw = 1.f;
    #pragma unroll
    for (int m = 1; m < MT; ++m) { pw *= kv; s_kp[tid*MT + m] = pw; }
    #pragma unroll
    for (int j = 0; j < 8; ++j) s_v[tid*8 + j] = v[j];
  }
  __syncthreads();

  if (tid < NMOM) {
    const int m = tid / 9, j = tid - m*9;
    float acc = 0.f;
    if (j == 0) {
      #pragma unroll 8
      for (int e = 0; e < PX; ++e) acc += s_kp[e*MT + m];
    } else {
      #pragma unroll 8
      for (int e = 0; e < PX; ++e) acc = fmaf(s_kp[e*MT + m], s_v[e*8 + (j-1)], acc);
    }
    const long long iq = llrintf(ldexpf(acc, 30 - m));   // per-m fixed-point scale 2^(30-m)
    atomicAdd(&a.MOM[(size_t)(scale*2 + b)*NMOM + tid], (unsigned long long)iq);
  }
}

// grid: 288 + 144 + 72 + 36 = 540 blocks
__global__ LB void qkvm_kernel(QkvmArgs a) {
  __shared__ __align__(16) float s_w[3072];
  __shared__ __align__(16) float s_sm[104];
  __shared__ __align__(16) float s_red[256*8];
  __shared__ __align__(16) float s_kp[64*MT];
  __shared__ __align__(16) float s_v[64*8];
  const int bid = blockIdx.x;
  if (bid < 288)      qkvm_body<4> (a, 0, 48,  9216, 0,     bid,     a.x0, a.w0, a.c0, s_w, s_sm, s_red, s_kp, s_v);
  else if (bid < 432) qkvm_body<8> (a, 1, 96,  2304, 18432, bid-288, a.x1, a.w1, a.c1, s_w, s_sm, s_red, s_kp, s_v);
  else if (bid < 504) qkvm_body<16>(a, 2, 192, 576,  23040, bid-432, a.x2, a.w2, a.c2, s_w, s_sm, s_red, s_kp, s_v);
  else                qkvm_body<32>(a, 3, 384, 144,  24192, bid-504, a.x3, a.w3, a.c3, s_w, s_sm, s_red, s_kp, s_v);
}

struct FinArgs {
  const float *Q, *P;
  const unsigned long long *MOM;
  const float *wg0, *bg0, *wg1, *bg1, *wg2, *bg2;
  float *Y;
};

// Per pixel: out[c] = (sum_m t_m M_m[c]) / (sum_m t_m d_m), t_m = q^m/m!; y = P + wg*out + bg.
__global__ LB void finish_kernel(FinArgs a) {
  __shared__ __align__(16) float smom[8*MT*12];   // 2688 floats, [sb][m][12]
  __shared__ float swg[3][64], sbg[3][8];
  const int tid = threadIdx.x;
  for (int i = tid; i < 8*MT*12; i += 256) smom[i] = 0.f;
  if (tid < 64) { swg[0][tid] = a.wg0[tid]; swg[1][tid] = a.wg1[tid]; swg[2][tid] = a.wg2[tid]; }
  if (tid < 8)  { sbg[0][tid] = a.bg0[tid]; sbg[1][tid] = a.bg1[tid]; sbg[2][tid] = a.bg2[tid]; }
  __syncthreads();
  for (int i = tid; i < 8*NMOM; i += 256) {
    const int sbi = i / NMOM, r = i - sbi*NMOM;
    const int m = r / 9, j = r - m*9;
    const long long ll = (long long)a.MOM[i];
    smom[sbi*(MT*12) + m*12 + j] = (float)ll * exp2f((float)(m - 30));
  }
  __syncthreads();
  const int g = blockIdx.x*256 + tid;
  if (g >= NSLOT) return;
  int scale, N, off, widx;
  if (g < 18432)      { scale=0; N=9216; off=0;     widx=0; }
  else if (g < 23040) { scale=1; N=2304; off=18432; widx=1; }
  else if (g < 24192) { scale=2; N=576;  off=23040; widx=2; }
  else                { scale=3; N=144;  off=24192; widx=1; }  // scale3 uses cca1 (faithful)
  const int b = (g - off >= N) ? 1 : 0;
  const int sb = scale*2 + b;
  const float q = a.Q[g];
  const float* mb = &smom[sb*(MT*12)];
  float t = 1.f, den = 0.f;
  float num[8];
  #pragma unroll
  for (int c = 0; c < 8; ++c) num[c] = 0.f;
  #pragma unroll
  for (int m = 0; m < MT; ++m) {
    const f32x4 a0 = *(const f32x4*)&mb[m*12];
    const f32x4 a1 = *(const f32x4*)&mb[m*12 + 4];
    const f32x4 a2 = *(const f32x4*)&mb[m*12 + 8];
    den    = fmaf(t, a0.x, den);
    num[0] = fmaf(t, a0.y, num[0]); num[1] = fmaf(t, a0.z, num[1]); num[2] = fmaf(t, a0.w, num[2]);
    num[3] = fmaf(t, a1.x, num[3]); num[4] = fmaf(t, a1.y, num[4]); num[5] = fmaf(t, a1.z, num[5]);
    num[6] = fmaf(t, a1.w, num[6]); num[7] = fmaf(t, a2.x, num[7]);
    if (m + 1 < MT) t *= q * (1.f/(float)(m+1));   // unrolled -> constant folded
  }
  const float inv = 1.f/den;
  float o8[8];
  #pragma unroll
  for (int c = 0; c < 8; ++c) o8[c] = num[c]*inv;
  const f32x4 pA = *(const f32x4*)&a.P[(size_t)g*8];
  const f32x4 pB = *(const f32x4*)&a.P[(size_t)g*8 + 4];
  const float pv[8] = {pA.x, pA.y, pA.z, pA.w, pB.x, pB.y, pB.z, pB.w};
  const float* wg = swg[widx];
  float y[8];
  #pragma unroll
  for (int o = 0; o < 8; ++o) {
    float s2 = pv[o] + sbg[widx][o];
    #pragma unroll
    for (int c = 0; c < 8; ++c) s2 = fmaf(wg[o*8 + c], o8[c], s2);
    y[o] = s2;
  }
  f32x4* Yp = (f32x4*)&a.Y[(size_t)g*8];
  Yp[0] = (f32x4){y[0], y[1], y[2], y[3]};
  Yp[1] = (f32x4){y[4], y[5], y[6], y[7]};
}

template<int HS>
__device__ inline void bilerp8(float* zo, const float* Yb, int h, int w) {
  constexpr float inv = (float)HS/96.0f;
  const float sy = (h + 0.5f)*inv - 0.5f;
  const float sx = (w + 0.5f)*inv - 0.5f;
  const int iy0 = (int)floorf(sy); const float fy = sy - (float)iy0;
  const int ix0 = (int)floorf(sx); const float fx = sx - (float)ix0;
  const int y0 = min(max(iy0, 0), HS-1), y1 = min(max(iy0 + 1, 0), HS-1);
  const int x0 = min(max(ix0, 0), HS-1), x1 = min(max(ix0 + 1, 0), HS-1);
  const float* p00 = &Yb[(size_t)(y0*HS + x0)*8];
  const float* p01 = &Yb[(size_t)(y0*HS + x1)*8];
  const float* p10 = &Yb[(size_t)(y1*HS + x0)*8];
  const float* p11 = &Yb[(size_t)(y1*HS + x1)*8];
  const float w00 = (1.f-fy)*(1.f-fx), w01 = (1.f-fy)*fx, w10 = fy*(1.f-fx), w11 = fy*fx;
  #pragma unroll
  for (int c = 0; c < 8; ++c)
    zo[c] = w00*p00[c] + w01*p01[c] + w10*p10[c] + w11*p11[c];
}

// 256-thread blocks x 72; split fmaf chains; 19 static output accumulators.
__global__ LB void head_kernel(const float* __restrict__ Y,
                               const float* wl0, const float* bl0,
                               const float* bn_s, const float* bn_b,
                               const float* bn_m, const float* bn_v,
                               const float* wl1, const float* bl1,
                               float* __restrict__ out) {
  __shared__ float s_wl0[1024], s_wl1[608];
  __shared__ float s_bl0[32], s_sc[32], s_sh[32], s_bl1[19];
  const int tid = threadIdx.x;
  for (int i = tid; i < 1024; i += 256) s_wl0[i] = wl0[i];
  for (int i = tid; i < 608;  i += 256) s_wl1[i] = wl1[i];
  if (tid < 32) {
    s_bl0[tid] = bl0[tid];
    const float sc = bn_s[tid] / sqrtf(bn_v[tid] + 1e-5f);
    s_sc[tid] = sc;
    s_sh[tid] = bn_b[tid] - bn_m[tid]*sc;
  }
  if (tid >= 32 && tid < 51) s_bl1[tid - 32] = bl1[tid - 32];
  __syncthreads();
  const int gp = blockIdx.x*256 + tid;   // exactly 18432 threads
  const int b = (gp >= 9216) ? 1 : 0;
  const int n = gp - b*9216;
  const int h = n / 96, w = n - h*96;
  float z[32];
  {
    const float4 zA = *(const float4*)&Y[(size_t)(b*9216 + n)*8];
    const float4 zB = *(const float4*)&Y[(size_t)(b*9216 + n)*8 + 4];
    z[0]=zA.x; z[1]=zA.y; z[2]=zA.z; z[3]=zA.w; z[4]=zB.x; z[5]=zB.y; z[6]=zB.z; z[7]=zB.w;
  }
  bilerp8<48>(z + 8,  &Y[(size_t)(18432 + b*2304)*8], h, w);
  bilerp8<24>(z + 16, &Y[(size_t)(23040 + b*576)*8],  h, w);
  bilerp8<12>(z + 24, &Y[(size_t)(24192 + b*144)*8],  h, w);
  float o19[19];
  #pragma unroll
  for (int j = 0; j < 19; ++j) o19[j] = s_bl1[j];
  #pragma unroll 1
  for (int o = 0; o < 32; ++o) {
    float sA = s_bl0[o], sB = 0.f;   // two chains halve the dependency stall
    #pragma unroll
    for (int c4 = 0; c4 < 4; ++c4) {
      const float4 wv = *(const float4*)&s_wl0[o*32 + c4*4];
      sA = fmaf(wv.x, z[c4*4+0], sA);
      sA = fmaf(wv.y, z[c4*4+1], sA);
      sA = fmaf(wv.z, z[c4*4+2], sA);
      sA = fmaf(wv.w, z[c4*4+3], sA);
    }
    #pragma unroll
    for (int c4 = 4; c4 < 8; ++c4) {
      const float4 wv = *(const float4*)&s_wl0[o*32 + c4*4];
      sB = fmaf(wv.x, z[c4*4+0], sB);
      sB = fmaf(wv.y, z[c4*4+1], sB);
      sB = fmaf(wv.z, z[c4*4+2], sB);
      sB = fmaf(wv.w, z[c4*4+3], sB);
    }
    const float t = fmaxf(fmaf(sA + sB, s_sc[o], s_sh[o]), 0.f);
    #pragma unroll
    for (int j = 0; j < 19; ++j) o19[j] = fmaf(s_wl1[j*32 + o], t, o19[j]);
  }
  #pragma unroll
  for (int j = 0; j < 19; ++j)
    out[((size_t)b*19 + j)*9216 + n] = o19[j];
}

extern "C" void kernel_launch(void* const* d_in, const int* in_sizes, int n_in,
                              void* d_out, int out_size, void* d_ws, size_t ws_size,
                              hipStream_t stream) {
  (void)in_sizes; (void)n_in; (void)out_size; (void)ws_size;
  const float* wq[3]; const float* bq[3]; const float* wk[3]; const float* bk[3];
  const float* wv[3]; const float* bv[3]; const float* wg[3]; const float* bg[3];
  for (int i = 0; i < 3; ++i) {
    const int base = 12 + i*8;
    wq[i] = (const float*)d_in[base + 0]; bq[i] = (const float*)d_in[base + 1];
    wk[i] = (const float*)d_in[base + 2]; bk[i] = (const float*)d_in[base + 3];
    wv[i] = (const float*)d_in[base + 4]; bv[i] = (const float*)d_in[base + 5];
    wg[i] = (const float*)d_in[base + 6]; bg[i] = (const float*)d_in[base + 7];
  }
  const int m4[4] = {0, 1, 2, 1};   // scale -> cca index (scale3 reuses cca1, faithful)

  // workspace (floats): P[8N] Q[N] MOM[8*252 u64] Y[8N]  (~1.6 MB)
  float* ws = (float*)d_ws;
  float* P = ws;
  float* Q = P + (size_t)NSLOT*8;
  unsigned long long* MOM = (unsigned long long*)(Q + NSLOT);   // 8B-aligned: offset 9*NSLOT*4 bytes, NSLOT even
  float* Y = (float*)(MOM + 8*NMOM);

  QkvmArgs qa;
  qa.x0 = (const float*)d_in[0]; qa.x1 = (const float*)d_in[1];
  qa.x2 = (const float*)d_in[2]; qa.x3 = (const float*)d_in[3];
  qa.w0 = (const float*)d_in[4];  qa.c0 = (const float*)d_in[5];
  qa.w1 = (const float*)d_in[6];  qa.c1 = (const float*)d_in[7];
  qa.w2 = (const float*)d_in[8];  qa.c2 = (const float*)d_in[9];
  qa.w3 = (const float*)d_in[10]; qa.c3 = (const float*)d_in[11];
  for (int s = 0; s < 4; ++s) {
    qa.wq[s] = wq[m4[s]]; qa.bq[s] = bq[m4[s]];
    qa.wk[s] = wk[m4[s]]; qa.bk[s] = bk[m4[s]];
    qa.wv[s] = wv[m4[s]]; qa.bv[s] = bv[m4[s]];
  }
  qa.P = P; qa.Q = Q; qa.MOM = MOM;

  FinArgs fa;
  fa.Q = Q; fa.P = P; fa.MOM = MOM;
  fa.wg0 = wg[0]; fa.bg0 = bg[0];
  fa.wg1 = wg[1]; fa.bg1 = bg[1];
  fa.wg2 = wg[2]; fa.bg2 = bg[2];
  fa.Y = Y;

  hipMemsetAsync(MOM, 0, (size_t)8*NMOM*sizeof(unsigned long long), stream);
  qkvm_kernel<<<540, 256, 0, stream>>>(qa);
  finish_kernel<<<96, 256, 0, stream>>>(fa);
  head_kernel<<<72, 256, 0, stream>>>(Y, (const float*)d_in[36], (const float*)d_in[37],
                                      (const float*)d_in[38], (const float*)d_in[39],
                                      (const float*)d_in[40], (const float*)d_in[41],
                                      (const float*)d_in[42], (const float*)d_in[43],
                                      (float*)d_out);
}